// Round 1
// baseline (196.733 us; speedup 1.0000x reference)
//
#include <hip/hip_runtime.h>
#include <hip/hip_bf16.h>
#include <cstdint>

#define BATCH 16
#define TTOT  4096
#define DIN   512
#define DOUT  512
#define NG    8

typedef float f32x4 __attribute__((ext_vector_type(4)));
typedef short s16x8 __attribute__((ext_vector_type(8)));

__device__ __forceinline__ short f2b(float f) {
    union { __bf16 b; short s; } u; u.b = (__bf16)f; return u.s;
}

// ---- Kernel 1: convert W (8x512x512 fp32) to bf16 in workspace ----
__global__ void wconv_kernel(const float* __restrict__ W, ushort* __restrict__ wbf) {
    int i = blockIdx.x * blockDim.x + threadIdx.x;   // each thread: 4 elems
    float4 v = reinterpret_cast<const float4*>(W)[i];
    ushort4 o;
    o.x = (ushort)f2b(v.x); o.y = (ushort)f2b(v.y);
    o.z = (ushort)f2b(v.z); o.w = (ushort)f2b(v.w);
    reinterpret_cast<ushort4*>(wbf)[i] = o;
}

// ---- Kernel 2: grouped GEMM, BM=64 BN=128 BK=64, 4 waves (2x2), dbuf LDS ----
template<bool WSB>
__launch_bounds__(256)
__global__ void gemm_kernel(const float* __restrict__ x,
                            const float* __restrict__ W,
                            const ushort* __restrict__ wbf,
                            const float* __restrict__ bias,
                            float* __restrict__ out) {
    __shared__ __align__(16) ushort As[2][64 * 64];    // 16 KB
    __shared__ __align__(16) ushort Bs[2][128 * 64];   // 32 KB

    const int tid  = threadIdx.x;
    const int lane = tid & 63;
    const int wid  = tid >> 6;
    const int wm   = wid >> 1;      // 0..1 : 32-row slab
    const int wn   = wid & 1;       // 0..1 : 64-col slab

    const int mt = blockIdx.x;
    const int bb = mt >> 6;                 // batch
    const int t0 = (mt & 63) << 6;          // token tile start (mult of 64)
    const int n0 = blockIdx.y << 7;         // output-col tile start

    // group lookup (boundaries are compile-time consts)
    int g = 0;
    if (t0 >= 256)  g++;
    if (t0 >= 768)  g++;
    if (t0 >= 1536) g++;
    if (t0 >= 1920) g++;
    if (t0 >= 2560) g++;
    if (t0 >= 3072) g++;
    if (t0 >= 3648) g++;

    // A staging: thread covers row=tid/4, 16 consecutive fp32 at col (tid%4)*16
    const int arow = tid >> 2;
    const int acol = (tid & 3) << 4;
    const float* aptr = x + ((size_t)(bb * TTOT + t0 + arow)) * DIN + acol;

    // staging registers
    float4 a0, a1, a2, a3;
    int4   bvi[4];
    float4 bw0[4], bw1[4];

    auto load_global = [&](int k0) {
        a0 = *reinterpret_cast<const float4*>(aptr + k0);
        a1 = *reinterpret_cast<const float4*>(aptr + k0 + 4);
        a2 = *reinterpret_cast<const float4*>(aptr + k0 + 8);
        a3 = *reinterpret_cast<const float4*>(aptr + k0 + 12);
#pragma unroll
        for (int p = 0; p < 4; ++p) {
            int idx = p * 256 + tid;
            int row = idx >> 3, seg = idx & 7;
            if (WSB) {
                bvi[p] = *reinterpret_cast<const int4*>(
                    wbf + ((size_t)((g << 9) + n0 + row)) * DIN + k0 + (seg << 3));
            } else {
                const float* wp = W + ((size_t)((g << 9) + n0 + row)) * DIN + k0 + (seg << 3);
                bw0[p] = *reinterpret_cast<const float4*>(wp);
                bw1[p] = *reinterpret_cast<const float4*>(wp + 4);
            }
        }
    };

    auto swz = [](int row, int bc) { return (row << 7) + (bc ^ ((row & 7) << 4)); };

    auto write_lds = [&](int buf) {
        char* ab = (char*)As[buf];
        char* bb_ = (char*)Bs[buf];
        s16x8 w0, w1;
        w0[0] = f2b(a0.x); w0[1] = f2b(a0.y); w0[2] = f2b(a0.z); w0[3] = f2b(a0.w);
        w0[4] = f2b(a1.x); w0[5] = f2b(a1.y); w0[6] = f2b(a1.z); w0[7] = f2b(a1.w);
        w1[0] = f2b(a2.x); w1[1] = f2b(a2.y); w1[2] = f2b(a2.z); w1[3] = f2b(a2.w);
        w1[4] = f2b(a3.x); w1[5] = f2b(a3.y); w1[6] = f2b(a3.z); w1[7] = f2b(a3.w);
        const int abase = acol << 1;   // byte col in bf16 tile
        *(s16x8*)(ab + swz(arow, abase))      = w0;
        *(s16x8*)(ab + swz(arow, abase + 16)) = w1;
#pragma unroll
        for (int p = 0; p < 4; ++p) {
            int idx = p * 256 + tid;
            int row = idx >> 3, seg = idx & 7;
            if (WSB) {
                *(int4*)(bb_ + swz(row, seg << 4)) = bvi[p];
            } else {
                s16x8 wv;
                wv[0] = f2b(bw0[p].x); wv[1] = f2b(bw0[p].y);
                wv[2] = f2b(bw0[p].z); wv[3] = f2b(bw0[p].w);
                wv[4] = f2b(bw1[p].x); wv[5] = f2b(bw1[p].y);
                wv[6] = f2b(bw1[p].z); wv[7] = f2b(bw1[p].w);
                *(s16x8*)(bb_ + swz(row, seg << 4)) = wv;
            }
        }
    };

    f32x4 acc[2][4];
#pragma unroll
    for (int mi = 0; mi < 2; ++mi)
#pragma unroll
        for (int ni = 0; ni < 4; ++ni)
            acc[mi][ni] = (f32x4){0.f, 0.f, 0.f, 0.f};

    const int colf = lane & 15;
    const int kgrp = lane >> 4;

    auto compute = [&](int buf) {
        const char* ab = (const char*)As[buf];
        const char* bb_ = (const char*)Bs[buf];
#pragma unroll
        for (int ks = 0; ks < 2; ++ks) {
            const int kb = ks * 64 + kgrp * 16;   // byte col of this lane's K-octet
            s16x8 af[2], bf[4];
#pragma unroll
            for (int mi = 0; mi < 2; ++mi)
                af[mi] = *(const s16x8*)(ab + swz(wm * 32 + mi * 16 + colf, kb));
#pragma unroll
            for (int ni = 0; ni < 4; ++ni)
                bf[ni] = *(const s16x8*)(bb_ + swz(wn * 64 + ni * 16 + colf, kb));
#pragma unroll
            for (int mi = 0; mi < 2; ++mi)
#pragma unroll
                for (int ni = 0; ni < 4; ++ni)
                    acc[mi][ni] = __builtin_amdgcn_mfma_f32_16x16x32_bf16(
                        af[mi], bf[ni], acc[mi][ni], 0, 0, 0);
        }
    };

    // prologue
    load_global(0);
    write_lds(0);
    __syncthreads();

    int buf = 0;
#pragma unroll 1
    for (int kt = 0; kt < 8; ++kt) {
        if (kt < 7) load_global((kt + 1) << 6);   // issue next tile's loads early
        compute(buf);
        if (kt < 7) write_lds(buf ^ 1);
        __syncthreads();
        buf ^= 1;
    }

    // epilogue: C/D layout col=lane&15, row=(lane>>4)*4+j
    const int rowg = lane >> 4;
#pragma unroll
    for (int ni = 0; ni < 4; ++ni) {
        const int o = n0 + wn * 64 + ni * 16 + colf;
        const float bv = bias[(g << 9) + o];
#pragma unroll
        for (int mi = 0; mi < 2; ++mi) {
            const int tt = t0 + wm * 32 + mi * 16 + rowg * 4;
            size_t ob = ((size_t)(bb * TTOT) + tt) * DOUT + o;
            f32x4 c = acc[mi][ni];
            out[ob]            = c[0] + bv;
            out[ob + DOUT]     = c[1] + bv;
            out[ob + 2 * DOUT] = c[2] + bv;
            out[ob + 3 * DOUT] = c[3] + bv;
        }
    }
}

extern "C" void kernel_launch(void* const* d_in, const int* in_sizes, int n_in,
                              void* d_out, int out_size, void* d_ws, size_t ws_size,
                              hipStream_t stream) {
    const float* x    = (const float*)d_in[0];
    const float* W    = (const float*)d_in[1];
    const float* bias = (const float*)d_in[2];
    float* out = (float*)d_out;

    const size_t wbytes = (size_t)NG * DOUT * DIN * sizeof(ushort);  // 4 MB
    ushort* wbf = (ushort*)d_ws;

    dim3 grid(BATCH * (TTOT / 64), DOUT / 128);

    if (ws_size >= wbytes) {
        wconv_kernel<<<(NG * DOUT * DIN / 4 + 255) / 256, 256, 0, stream>>>(W, wbf);
        gemm_kernel<true><<<grid, 256, 0, stream>>>(x, W, wbf, bias, out);
    } else {
        gemm_kernel<false><<<grid, 256, 0, stream>>>(x, W, wbf, bias, out);
    }
}